// Round 18
// baseline (297.128 us; speedup 1.0000x reference)
//
#include <hip/hip_runtime.h>
#include <hip/hip_fp16.h>

#define NN 100000
#define EE 1600000
#define HH 128
#define GG 64
#define CC 32
#define ETOT (EE + NN)   // edges + self-loops

// bucketed-partition params
#define NB 256                      // dst buckets
#define BS 392                      // nodes per bucket (256*392 >= 100000)
#define CHUNK 8192                  // edges per partition block
#define NBLK ((EE + CHUNK - 1) / CHUNK)   // 196
#define MATL (NB * NBLK)            // 50176

typedef _Float16 half8 __attribute__((ext_vector_type(8)));
typedef float f32x4 __attribute__((ext_vector_type(4)));
typedef float floatx2 __attribute__((ext_vector_type(2)));

// ---------------- prep: W transpose->fp16 (blocks 0-2) + zero accumulators (blocks 3+) ----------------
__global__ __launch_bounds__(256) void k_prep(const float* __restrict__ W1, const float* __restrict__ W2,
                                              const float* __restrict__ W3, __half* __restrict__ wt,
                                              float* __restrict__ pooled, float* __restrict__ gcnt,
                                              unsigned char* __restrict__ t8) {
    if (blockIdx.x < 3) {
        __shared__ float sW[HH * (HH + 1)];
        const float* W = (blockIdx.x == 0) ? W1 : (blockIdx.x == 1) ? W2 : W3;
        __half* out = wt + (size_t)blockIdx.x * HH * HH;
        int t = threadIdx.x;
        #pragma unroll 4
        for (int i = 0; i < 64; i++) {
            int idx = i * 256 + t;
            sW[(idx >> 7) * (HH + 1) + (idx & 127)] = W[idx];
        }
        __syncthreads();
        #pragma unroll 4
        for (int i = 0; i < 64; i++) {
            int o = i * 256 + t;
            int n = o >> 7, k = o & 127;
            out[o] = __float2half(sW[k * (HH + 1) + n]);
        }
    } else {
        int i = (blockIdx.x - 3) * 256 + threadIdx.x;
        if (i < GG * HH) pooled[i] = 0.f;
        if (i < GG) gcnt[i] = 0.f;
        if (i < HH) t8[(size_t)NN * HH + i] = 0;   // fp8 0.0 == 0x00
    }
}

// ---------------- generalized 3-phase exclusive scan (multi-block, parallel) ----------------
__global__ __launch_bounds__(1024) void k_psumG(const int* __restrict__ in, int* __restrict__ bsum, int L) {
    __shared__ int red[1024];
    int i = blockIdx.x * 1024 + threadIdx.x;
    red[threadIdx.x] = (i < L) ? in[i] : 0;
    __syncthreads();
    for (int off = 512; off > 0; off >>= 1) {
        if (threadIdx.x < off) red[threadIdx.x] += red[threadIdx.x + off];
        __syncthreads();
    }
    if (threadIdx.x == 0) bsum[blockIdx.x] = red[0];
}
__global__ __launch_bounds__(1024) void k_bscanG(const int* __restrict__ bsum, int* __restrict__ boff, int nb) {
    __shared__ int s[1024];
    int t = threadIdx.x;
    s[t] = (t < nb) ? bsum[t] : 0;
    __syncthreads();
    for (int off = 1; off < 1024; off <<= 1) {
        int tmp = (t >= off) ? s[t - off] : 0;
        __syncthreads();
        s[t] += tmp;
        __syncthreads();
    }
    if (t < nb) boff[t] = s[t] - bsum[t];
}
__global__ __launch_bounds__(1024) void k_localG(const int* __restrict__ in, const int* __restrict__ boff,
                                                 int* __restrict__ off, int L, int total) {
    __shared__ int s[1024];
    int i = blockIdx.x * 1024 + threadIdx.x, t = threadIdx.x;
    int v = (i < L) ? in[i] : 0;
    s[t] = v;
    __syncthreads();
    for (int o = 1; o < 1024; o <<= 1) {
        int tmp = (t >= o) ? s[t - o] : 0;
        __syncthreads();
        s[t] += tmp;
        __syncthreads();
    }
    if (i < L) off[i] = boff[blockIdx.x] + s[t] - v;
    if (i == L - 1) off[L] = total;
}

// ---------------- phase A1: per-block bucket histogram -> mat[bucket][block] ----------------
__global__ __launch_bounds__(256) void k_hist(const int* __restrict__ dst, int* __restrict__ mat) {
    __shared__ int hist[NB];
    int t = threadIdx.x, blk = blockIdx.x;
    hist[t] = 0;
    __syncthreads();
    int base = blk * CHUNK;
    #pragma unroll 4
    for (int it = 0; it < CHUNK / 256; it++) {
        int e = base + it * 256 + t;
        if (e < EE) atomicAdd(&hist[dst[e] / BS], 1);
    }
    __syncthreads();
    mat[t * NBLK + blk] = hist[t];
}

// ---------------- phase A2: scatter edges into per-(block,bucket) runs ----------------
__global__ __launch_bounds__(256) void k_binscatter(const int* __restrict__ src, const int* __restrict__ dst,
                                                    const int* __restrict__ matscan, int* __restrict__ staged) {
    __shared__ int lcur[NB];
    int t = threadIdx.x, blk = blockIdx.x;
    lcur[t] = matscan[t * NBLK + blk];
    __syncthreads();
    int base = blk * CHUNK;
    #pragma unroll 4
    for (int it = 0; it < CHUNK / 256; it++) {
        int e = base + it * 256 + t;
        if (e < EE) {
            int d = dst[e], s = src[e];
            int b = d / BS;
            int pos = atomicAdd(&lcur[b], 1);
            staged[pos] = s | ((d - b * BS) << 17);     // src 17b | dst_local 9b
        }
    }
}

// ---------------- phase B1: per-bucket degree counts (incl self) + dinv ----------------
__global__ __launch_bounds__(256) void k_bcount(const int* __restrict__ matscan, const int* __restrict__ staged,
                                                int* __restrict__ counts, float* __restrict__ dinv) {
    __shared__ int cnt[BS];
    int t = threadIdx.x, b = blockIdx.x;
    for (int i = t; i < BS; i += 256) cnt[i] = 1;       // self-loop
    __syncthreads();
    int beg = matscan[b * NBLK], end = matscan[(b + 1) * NBLK];
    for (int p = beg + t; p < end; p += 256) atomicAdd(&cnt[staged[p] >> 17], 1);
    __syncthreads();
    int nb0 = b * BS;
    for (int i = t; i < BS; i += 256) {
        int n = nb0 + i;
        if (n < NN) { int c = cnt[i]; counts[n] = c; dinv[n] = rsqrtf((float)c); }
    }
}

// ---------------- phase B2: place edges into CSR (L2-local per bucket) ----------------
__global__ __launch_bounds__(256) void k_place(const int* __restrict__ matscan, const int* __restrict__ staged,
                                               const int* __restrict__ row_off, int* __restrict__ csr_src) {
    __shared__ int rof[BS];
    __shared__ int lcur[BS];
    int t = threadIdx.x, b = blockIdx.x;
    int nb0 = b * BS;
    for (int i = t; i < BS; i += 256) {
        int n = nb0 + i;
        int r = (n < NN) ? row_off[n] : 0;
        rof[i] = r; lcur[i] = 1;
        if (n < NN) csr_src[r] = n;                     // self edge in slot 0
    }
    __syncthreads();
    int beg = matscan[b * NBLK], end = matscan[(b + 1) * NBLK];
    for (int p = beg + t; p < end; p += 256) {
        int pk = staged[p];
        int dl = pk >> 17, s = pk & 0x1FFFF;
        int pos = rof[dl] + atomicAdd(&lcur[dl], 1);
        csr_src[pos] = s;
    }
}

// ---------------- MFMA GEMM: T8[r][c](fp8 e4m3) = dinv[r] * (A[r][:] @ W)[c] ----------------
// F32IN=1: A node-major fp32 (layer 1). F32IN=0: A node-major fp16 (h16).
template<int F32IN>
__global__ __launch_bounds__(256) void k_gemm(const void* __restrict__ Ap, const __half* __restrict__ Wt,
                                              const float* __restrict__ dinv, unsigned char* __restrict__ T) {
    __shared__ __align__(16) char sm[64 * 1024];
    char* sA = sm;                 // 128 rows x 256B fp16, XOR-swizzled
    char* sB = sm + 32 * 1024;
    int tid = threadIdx.x;
    int r0 = blockIdx.x * 128;

    #pragma unroll
    for (int it = 0; it < 8; it++) {
        int p = (tid + it * 256) * 16;            // LDS byte (fp16 tile)
        int lrow = p >> 8;
        int grow = r0 + lrow; if (grow > NN - 1) grow = NN - 1;
        uint4 v;
        if (F32IN) {
            const char* Ab = (const char*)Ap;
            const float4* f0 = (const float4*)(Ab + (size_t)grow * 512 + (p & 255) * 2);
            float4 a = f0[0], b = f0[1];
            union { uint4 u; __half2 h[4]; } pk;
            pk.h[0] = __floats2half2_rn(a.x, a.y);
            pk.h[1] = __floats2half2_rn(a.z, a.w);
            pk.h[2] = __floats2half2_rn(b.x, b.y);
            pk.h[3] = __floats2half2_rn(b.z, b.w);
            v = pk.u;
        } else {
            const char* Ab = (const char*)Ap;
            v = *(const uint4*)(Ab + (size_t)grow * 256 + (p & 255));
        }
        *(uint4*)(sA + (p ^ ((lrow & 7) << 4))) = v;
    }
    const char* Wb = (const char*)Wt;
    #pragma unroll
    for (int it = 0; it < 8; it++) {
        int p = (tid + it * 256) * 16;
        int lrow = p >> 8;
        uint4 v = *(const uint4*)(Wb + p);
        *(uint4*)(sB + (p ^ ((lrow & 7) << 4))) = v;
    }
    __syncthreads();

    int w = tid >> 6;
    int lane = tid & 63;
    int q = lane >> 4;
    int ln = lane & 15;
    int wr = (w >> 1) * 64;
    int wc = (w & 1) * 64;

    f32x4 acc[4][4];
    #pragma unroll
    for (int a = 0; a < 4; a++)
        #pragma unroll
        for (int b = 0; b < 4; b++) acc[a][b] = (f32x4)0.f;

    #pragma unroll
    for (int ks = 0; ks < 4; ks++) {
        int koff = ks * 64 + q * 16;
        half8 af[4], bf[4];
        #pragma unroll
        for (int mi = 0; mi < 4; mi++) {
            int row = wr + mi * 16 + ln;
            af[mi] = *(half8*)(sA + row * 256 + (koff ^ ((row & 7) << 4)));
        }
        #pragma unroll
        for (int ni = 0; ni < 4; ni++) {
            int row = wc + ni * 16 + ln;
            bf[ni] = *(half8*)(sB + row * 256 + (koff ^ ((row & 7) << 4)));
        }
        #pragma unroll
        for (int mi = 0; mi < 4; mi++)
            #pragma unroll
            for (int ni = 0; ni < 4; ni++)
                acc[mi][ni] = __builtin_amdgcn_mfma_f32_16x16x32_f16(af[mi], bf[ni], acc[mi][ni], 0, 0, 0);
    }

    float dv[4][4];
    #pragma unroll
    for (int mi = 0; mi < 4; mi++)
        #pragma unroll
        for (int r = 0; r < 4; r++) {
            int grow = r0 + wr + mi * 16 + q * 4 + r;
            dv[mi][r] = dinv[grow < NN ? grow : 0];
        }
    #pragma unroll
    for (int mi = 0; mi < 4; mi++) {
        #pragma unroll
        for (int r = 0; r < 4; r++) {
            int grow = r0 + wr + mi * 16 + q * 4 + r;
            if (grow < NN) {
                #pragma unroll
                for (int ni = 0; ni < 4; ni++) {
                    int gcol = wc + ni * 16 + ln;
                    float v = acc[mi][ni][r] * dv[mi][r];
                    unsigned qb = (unsigned)__builtin_amdgcn_cvt_pk_fp8_f32(v, v, 0, false) & 0xffu;
                    T[(size_t)grow * HH + gcol] = (unsigned char)qb;
                }
            }
        }
    }
}

// ---------------- aggregation: O[n](fp16) = relu?( dinv[n]*sum_{csr} T8[src] + bias ) ----------------
// wave = 1 node; lane = (eslot 0..3) x (li 0..15: 8B of the 128B fp8 row).
// 4-eslot geometry: acc state halves (4 regs) -> reduce tail = 2 rounds x 4 regs (16 instrs
// vs 48 at 8-eslot). Decode work per edge unchanged. Software pipeline retained.
__global__ __launch_bounds__(256) void k_agg(const unsigned char* __restrict__ T, __half* __restrict__ O,
                                             const int* __restrict__ row_off, const int* __restrict__ csr_src,
                                             const float* __restrict__ dinv,
                                             const float* __restrict__ bias, int relu) {
    int gt = blockIdx.x * blockDim.x + threadIdx.x;
    int n = gt >> 6;
    if (n >= NN) return;
    int lane = threadIdx.x & 63;
    int eslot = lane >> 4;                     // 0..3 edge slot
    int li = lane & 15;                        // 8B chunk of the 128B row

    int beg = row_off[n], end = row_off[n + 1];
    int nit = (end - beg + 3) >> 2;            // >= 1 (self edge)

    floatx2 acc2[4];
    #pragma unroll
    for (int c = 0; c < 4; c++) acc2[c] = (floatx2)0.f;

    // prologue: issue gather 0
    int p = beg + eslot;
    int s0raw = csr_src[p];                    // csr_src padded: always-valid address
    int s0 = (p < end) ? s0raw : NN;           // fp8 zero row for invalid slots
    uint2 r0 = *(const uint2*)(T + ((size_t)s0 << 7) + li * 8);

    for (int i = 1; i < nit; i++) {
        p += 4;
        // issue gather i before converting gather i-1
        int s1raw = csr_src[p];
        int s1 = (p < end) ? s1raw : NN;
        uint2 r1 = *(const uint2*)(T + ((size_t)s1 << 7) + li * 8);
        acc2[0] += __builtin_amdgcn_cvt_pk_f32_fp8(r0.x, false);
        acc2[1] += __builtin_amdgcn_cvt_pk_f32_fp8(r0.x, true);
        acc2[2] += __builtin_amdgcn_cvt_pk_f32_fp8(r0.y, false);
        acc2[3] += __builtin_amdgcn_cvt_pk_f32_fp8(r0.y, true);
        r0 = r1;
    }
    // epilogue: convert last gather
    acc2[0] += __builtin_amdgcn_cvt_pk_f32_fp8(r0.x, false);
    acc2[1] += __builtin_amdgcn_cvt_pk_f32_fp8(r0.x, true);
    acc2[2] += __builtin_amdgcn_cvt_pk_f32_fp8(r0.y, false);
    acc2[3] += __builtin_amdgcn_cvt_pk_f32_fp8(r0.y, true);

    // pack to fp16 pairs, reduce across 4 edge slots (xor 16, 32)
    union { __half2 h; int i; } r[4];
    #pragma unroll
    for (int j = 0; j < 4; j++) r[j].h = __floats2half2_rn(acc2[j].x, acc2[j].y);
    #pragma unroll
    for (int m = 16; m <= 32; m <<= 1) {
        #pragma unroll
        for (int j = 0; j < 4; j++) {
            union { __half2 h; int i; } v;
            v.i = __shfl_xor(r[j].i, m, 64);
            r[j].h = __hadd2(r[j].h, v.h);
        }
    }

    if (eslot == 0) {                          // lanes 0..15 hold li = 0..15 (8 cols each)
        float dn = dinv[n];
        float o[8];
        #pragma unroll
        for (int j = 0; j < 4; j++) {
            float2 f = __half22float2(r[j].h);
            o[2 * j] = f.x; o[2 * j + 1] = f.y;
        }
        const float* bp = bias + li * 8;
        #pragma unroll
        for (int k = 0; k < 8; k++) {
            o[k] = dn * o[k] + bp[k];
            if (relu) o[k] = fmaxf(o[k], 0.f);
        }
        union { uint4 u; __half2 h2[4]; } pk;
        #pragma unroll
        for (int j = 0; j < 4; j++) pk.h2[j] = __floats2half2_rn(o[2 * j], o[2 * j + 1]);
        *(uint4*)((char*)O + (size_t)n * 256 + li * 16) = pk.u;
    }
}

// ---------------- pooling: batch sorted -> run-length accumulate (node-major fp16 in) ----------------
__global__ __launch_bounds__(128) void k_pool(const __half* __restrict__ Hm, const int* __restrict__ batch,
                                              float* __restrict__ pooled, float* __restrict__ gcnt) {
    int j = threadIdx.x;
    int n0 = blockIdx.x * 64;
    int nend = n0 + 64; if (nend > NN) nend = NN;
    float acc = 0.f;
    int gcur = batch[n0];
    int run = 0;
    for (int n = n0; n < nend; n++) {
        int g = batch[n];
        if (g != gcur) {
            atomicAdd(&pooled[gcur * HH + j], acc);
            if (j == 0) atomicAdd(&gcnt[gcur], (float)run);
            acc = 0.f; run = 0; gcur = g;
        }
        acc += __half2float(Hm[(size_t)n * HH + j]);
        run++;
    }
    atomicAdd(&pooled[gcur * HH + j], acc);
    if (j == 0) atomicAdd(&gcnt[gcur], (float)run);
}

// ---------------- classifier ----------------
__global__ void k_classify(const float* __restrict__ pooled, const float* __restrict__ gcnt,
                           const float* __restrict__ Wc, const float* __restrict__ bc,
                           float* __restrict__ out) {
    int idx = blockIdx.x * blockDim.x + threadIdx.x;
    if (idx >= GG * CC) return;
    int g = idx >> 5, c = idx & 31;
    float inv = 1.f / fmaxf(gcnt[g], 1.f);
    float acc = bc[c];
    for (int k = 0; k < HH; k++) acc += pooled[g * HH + k] * inv * Wc[k * CC + c];
    out[idx] = acc;
}

extern "C" void kernel_launch(void* const* d_in, const int* in_sizes, int n_in,
                              void* d_out, int out_size, void* d_ws, size_t ws_size,
                              hipStream_t stream) {
    const float* x     = (const float*)d_in[0];
    const int*   ei    = (const int*)d_in[1];
    const int*   batch = (const int*)d_in[2];
    const float* W1 = (const float*)d_in[3];  const float* b1 = (const float*)d_in[4];
    const float* W2 = (const float*)d_in[5];  const float* b2 = (const float*)d_in[6];
    const float* W3 = (const float*)d_in[7];  const float* b3 = (const float*)d_in[8];
    const float* Wc = (const float*)d_in[9];  const float* bc = (const float*)d_in[10];
    float* out = (float*)d_out;

    const int* src = ei;
    const int* dst = ei + EE;

    char* w = (char*)d_ws;
    __half*        h16     = (__half*)w;        w += (size_t)NN * HH * sizeof(__half);     // 25.6 MB node-major
    unsigned char* t8      = (unsigned char*)w; w += (size_t)(NN + 1) * HH;                // 12.8 MB fp8 + zero row
    __half*        wt16    = (__half*)w;        w += (size_t)3 * HH * HH * sizeof(__half);
    float*         dinv    = (float*)w;         w += (size_t)NN * sizeof(float);
    int*           csr_src = (int*)w;           w += (size_t)(ETOT + 32) * sizeof(int);    // +pad for slot overread
    int*           staged  = (int*)w;           w += (size_t)EE * sizeof(int);
    int*           mat     = (int*)w;           w += (size_t)MATL * sizeof(int);
    int*           matscan = (int*)w;           w += (size_t)(MATL + 1) * sizeof(int);
    int*           row_off = (int*)w;           w += (size_t)(NN + 1) * sizeof(int);
    int*           counts  = (int*)w;           w += (size_t)NN * sizeof(int);
    int*           bsum    = (int*)w;           w += (size_t)1024 * sizeof(int);
    int*           boff    = (int*)w;           w += (size_t)1024 * sizeof(int);
    float*         pooled  = (float*)w;         w += (size_t)GG * HH * sizeof(float);
    float*         gcnt    = (float*)w;         w += (size_t)GG * sizeof(float);

    const int matblk = (MATL + 1023) / 1024;   // 49
    const int cntblk = (NN + 1023) / 1024;     // 98

    // prep (W transpose + accumulator init, one kernel)
    k_prep <<<3 + (GG * HH + 255) / 256, 256, 0, stream>>>(W1, W2, W3, wt16, pooled, gcnt, t8);

    // CSR build: bucketed two-phase partition (multi-block scans)
    k_hist      <<<NBLK, 256, 0, stream>>>(dst, mat);
    k_psumG     <<<matblk, 1024, 0, stream>>>(mat, bsum, MATL);
    k_bscanG    <<<1, 1024, 0, stream>>>(bsum, boff, matblk);
    k_localG    <<<matblk, 1024, 0, stream>>>(mat, boff, matscan, MATL, EE);
    k_binscatter<<<NBLK, 256, 0, stream>>>(src, dst, matscan, staged);
    k_bcount    <<<NB, 256, 0, stream>>>(matscan, staged, counts, dinv);
    k_psumG     <<<cntblk, 1024, 0, stream>>>(counts, bsum, NN);
    k_bscanG    <<<1, 1024, 0, stream>>>(bsum, boff, cntblk);
    k_localG    <<<cntblk, 1024, 0, stream>>>(counts, boff, row_off, NN, ETOT);
    k_place     <<<NB, 256, 0, stream>>>(matscan, staged, row_off, csr_src);

    const int gemm_grid = (NN + 127) / 128;   // 782
    const int agg_grid  = NN * 64 / 256;      // 25000 (one wave per node)

    // layer 1 (fp32 input staged+converted in-kernel)
    k_gemm<1><<<gemm_grid, 256, 0, stream>>>(x, wt16,                dinv, t8);
    k_agg    <<<agg_grid, 256, 0, stream>>>(t8, h16, row_off, csr_src, dinv, b1, 1);
    // layer 2
    k_gemm<0><<<gemm_grid, 256, 0, stream>>>(h16, wt16 + HH * HH,    dinv, t8);
    k_agg    <<<agg_grid, 256, 0, stream>>>(t8, h16, row_off, csr_src, dinv, b2, 1);
    // layer 3 (no relu)
    k_gemm<0><<<gemm_grid, 256, 0, stream>>>(h16, wt16 + 2 * HH * HH, dinv, t8);
    k_agg    <<<agg_grid, 256, 0, stream>>>(t8, h16, row_off, csr_src, dinv, b3, 0);

    // pool + classify
    k_pool<<<(NN + 63) / 64, 128, 0, stream>>>(h16, batch, pooled, gcnt);
    k_classify<<<(GG * CC + 255) / 256, 256, 0, stream>>>(pooled, gcnt, Wc, bc, out);
}

// Round 20
// 289.076 us; speedup vs baseline: 1.0279x; 1.0279x over previous
//
#include <hip/hip_runtime.h>
#include <hip/hip_fp16.h>

#define NN 100000
#define EE 1600000
#define HH 128
#define GG 64
#define CC 32
#define ETOT (EE + NN)   // edges + self-loops

// bucketed-partition params
#define NB 256                      // dst buckets
#define BS 392                      // nodes per bucket (256*392 >= 100000)
#define CHUNK 8192                  // edges per partition block
#define NBLK ((EE + CHUNK - 1) / CHUNK)   // 196
#define MATL (NB * NBLK)            // 50176

typedef _Float16 half8 __attribute__((ext_vector_type(8)));
typedef float f32x4 __attribute__((ext_vector_type(4)));
typedef float floatx2 __attribute__((ext_vector_type(2)));

// ---------------- prep: W transpose->fp16 (blocks 0-2) + zero accumulators (blocks 3+) ----------------
__global__ __launch_bounds__(256) void k_prep(const float* __restrict__ W1, const float* __restrict__ W2,
                                              const float* __restrict__ W3, __half* __restrict__ wt,
                                              float* __restrict__ pooled, float* __restrict__ gcnt,
                                              unsigned char* __restrict__ t8) {
    if (blockIdx.x < 3) {
        __shared__ float sW[HH * (HH + 1)];
        const float* W = (blockIdx.x == 0) ? W1 : (blockIdx.x == 1) ? W2 : W3;
        __half* out = wt + (size_t)blockIdx.x * HH * HH;
        int t = threadIdx.x;
        #pragma unroll 4
        for (int i = 0; i < 64; i++) {
            int idx = i * 256 + t;
            sW[(idx >> 7) * (HH + 1) + (idx & 127)] = W[idx];
        }
        __syncthreads();
        #pragma unroll 4
        for (int i = 0; i < 64; i++) {
            int o = i * 256 + t;
            int n = o >> 7, k = o & 127;
            out[o] = __float2half(sW[k * (HH + 1) + n]);
        }
    } else {
        int i = (blockIdx.x - 3) * 256 + threadIdx.x;
        if (i < GG * HH) pooled[i] = 0.f;
        if (i < GG) gcnt[i] = 0.f;
        if (i < HH) t8[(size_t)NN * HH + i] = 0;   // fp8 0.0 == 0x00
    }
}

// ---------------- generalized 3-phase exclusive scan (multi-block, parallel) ----------------
__global__ __launch_bounds__(1024) void k_psumG(const int* __restrict__ in, int* __restrict__ bsum, int L) {
    __shared__ int red[1024];
    int i = blockIdx.x * 1024 + threadIdx.x;
    red[threadIdx.x] = (i < L) ? in[i] : 0;
    __syncthreads();
    for (int off = 512; off > 0; off >>= 1) {
        if (threadIdx.x < off) red[threadIdx.x] += red[threadIdx.x + off];
        __syncthreads();
    }
    if (threadIdx.x == 0) bsum[blockIdx.x] = red[0];
}
__global__ __launch_bounds__(1024) void k_bscanG(const int* __restrict__ bsum, int* __restrict__ boff, int nb) {
    __shared__ int s[1024];
    int t = threadIdx.x;
    s[t] = (t < nb) ? bsum[t] : 0;
    __syncthreads();
    for (int off = 1; off < 1024; off <<= 1) {
        int tmp = (t >= off) ? s[t - off] : 0;
        __syncthreads();
        s[t] += tmp;
        __syncthreads();
    }
    if (t < nb) boff[t] = s[t] - bsum[t];
}
__global__ __launch_bounds__(1024) void k_localG(const int* __restrict__ in, const int* __restrict__ boff,
                                                 int* __restrict__ off, int L, int total) {
    __shared__ int s[1024];
    int i = blockIdx.x * 1024 + threadIdx.x, t = threadIdx.x;
    int v = (i < L) ? in[i] : 0;
    s[t] = v;
    __syncthreads();
    for (int o = 1; o < 1024; o <<= 1) {
        int tmp = (t >= o) ? s[t - o] : 0;
        __syncthreads();
        s[t] += tmp;
        __syncthreads();
    }
    if (i < L) off[i] = boff[blockIdx.x] + s[t] - v;
    if (i == L - 1) off[L] = total;
}

// ---------------- phase A1: per-block bucket histogram -> mat[bucket][block] ----------------
__global__ __launch_bounds__(256) void k_hist(const int* __restrict__ dst, int* __restrict__ mat) {
    __shared__ int hist[NB];
    int t = threadIdx.x, blk = blockIdx.x;
    hist[t] = 0;
    __syncthreads();
    int base = blk * CHUNK;
    #pragma unroll 4
    for (int it = 0; it < CHUNK / 256; it++) {
        int e = base + it * 256 + t;
        if (e < EE) atomicAdd(&hist[dst[e] / BS], 1);
    }
    __syncthreads();
    mat[t * NBLK + blk] = hist[t];
}

// ---------------- phase A2: scatter edges into per-(block,bucket) runs ----------------
__global__ __launch_bounds__(256) void k_binscatter(const int* __restrict__ src, const int* __restrict__ dst,
                                                    const int* __restrict__ matscan, int* __restrict__ staged) {
    __shared__ int lcur[NB];
    int t = threadIdx.x, blk = blockIdx.x;
    lcur[t] = matscan[t * NBLK + blk];
    __syncthreads();
    int base = blk * CHUNK;
    #pragma unroll 4
    for (int it = 0; it < CHUNK / 256; it++) {
        int e = base + it * 256 + t;
        if (e < EE) {
            int d = dst[e], s = src[e];
            int b = d / BS;
            int pos = atomicAdd(&lcur[b], 1);
            staged[pos] = s | ((d - b * BS) << 17);     // src 17b | dst_local 9b
        }
    }
}

// ---------------- phase B1: per-bucket degree counts (incl self) + dinv ----------------
__global__ __launch_bounds__(256) void k_bcount(const int* __restrict__ matscan, const int* __restrict__ staged,
                                                int* __restrict__ counts, float* __restrict__ dinv) {
    __shared__ int cnt[BS];
    int t = threadIdx.x, b = blockIdx.x;
    for (int i = t; i < BS; i += 256) cnt[i] = 1;       // self-loop
    __syncthreads();
    int beg = matscan[b * NBLK], end = matscan[(b + 1) * NBLK];
    for (int p = beg + t; p < end; p += 256) atomicAdd(&cnt[staged[p] >> 17], 1);
    __syncthreads();
    int nb0 = b * BS;
    for (int i = t; i < BS; i += 256) {
        int n = nb0 + i;
        if (n < NN) { int c = cnt[i]; counts[n] = c; dinv[n] = rsqrtf((float)c); }
    }
}

// ---------------- phase B2: place edges into CSR (L2-local per bucket) ----------------
__global__ __launch_bounds__(256) void k_place(const int* __restrict__ matscan, const int* __restrict__ staged,
                                               const int* __restrict__ row_off, int* __restrict__ csr_src) {
    __shared__ int rof[BS];
    __shared__ int lcur[BS];
    int t = threadIdx.x, b = blockIdx.x;
    int nb0 = b * BS;
    for (int i = t; i < BS; i += 256) {
        int n = nb0 + i;
        int r = (n < NN) ? row_off[n] : 0;
        rof[i] = r; lcur[i] = 1;
        if (n < NN) csr_src[r] = n;                     // self edge in slot 0
    }
    __syncthreads();
    int beg = matscan[b * NBLK], end = matscan[(b + 1) * NBLK];
    for (int p = beg + t; p < end; p += 256) {
        int pk = staged[p];
        int dl = pk >> 17, s = pk & 0x1FFFF;
        int pos = rof[dl] + atomicAdd(&lcur[dl], 1);
        csr_src[pos] = s;
    }
}

// ---------------- MFMA GEMM: T8[r][c](fp8 e4m3) = dinv[r] * (A[r][:] @ W)[c] ----------------
// F32IN=1: A node-major fp32 (layer 1). F32IN=0: A node-major fp16 (h16).
template<int F32IN>
__global__ __launch_bounds__(256) void k_gemm(const void* __restrict__ Ap, const __half* __restrict__ Wt,
                                              const float* __restrict__ dinv, unsigned char* __restrict__ T) {
    __shared__ __align__(16) char sm[64 * 1024];
    char* sA = sm;                 // 128 rows x 256B fp16, XOR-swizzled
    char* sB = sm + 32 * 1024;
    int tid = threadIdx.x;
    int r0 = blockIdx.x * 128;

    #pragma unroll
    for (int it = 0; it < 8; it++) {
        int p = (tid + it * 256) * 16;            // LDS byte (fp16 tile)
        int lrow = p >> 8;
        int grow = r0 + lrow; if (grow > NN - 1) grow = NN - 1;
        uint4 v;
        if (F32IN) {
            const char* Ab = (const char*)Ap;
            const float4* f0 = (const float4*)(Ab + (size_t)grow * 512 + (p & 255) * 2);
            float4 a = f0[0], b = f0[1];
            union { uint4 u; __half2 h[4]; } pk;
            pk.h[0] = __floats2half2_rn(a.x, a.y);
            pk.h[1] = __floats2half2_rn(a.z, a.w);
            pk.h[2] = __floats2half2_rn(b.x, b.y);
            pk.h[3] = __floats2half2_rn(b.z, b.w);
            v = pk.u;
        } else {
            const char* Ab = (const char*)Ap;
            v = *(const uint4*)(Ab + (size_t)grow * 256 + (p & 255));
        }
        *(uint4*)(sA + (p ^ ((lrow & 7) << 4))) = v;
    }
    const char* Wb = (const char*)Wt;
    #pragma unroll
    for (int it = 0; it < 8; it++) {
        int p = (tid + it * 256) * 16;
        int lrow = p >> 8;
        uint4 v = *(const uint4*)(Wb + p);
        *(uint4*)(sB + (p ^ ((lrow & 7) << 4))) = v;
    }
    __syncthreads();

    int w = tid >> 6;
    int lane = tid & 63;
    int q = lane >> 4;
    int ln = lane & 15;
    int wr = (w >> 1) * 64;
    int wc = (w & 1) * 64;

    f32x4 acc[4][4];
    #pragma unroll
    for (int a = 0; a < 4; a++)
        #pragma unroll
        for (int b = 0; b < 4; b++) acc[a][b] = (f32x4)0.f;

    #pragma unroll
    for (int ks = 0; ks < 4; ks++) {
        int koff = ks * 64 + q * 16;
        half8 af[4], bf[4];
        #pragma unroll
        for (int mi = 0; mi < 4; mi++) {
            int row = wr + mi * 16 + ln;
            af[mi] = *(half8*)(sA + row * 256 + (koff ^ ((row & 7) << 4)));
        }
        #pragma unroll
        for (int ni = 0; ni < 4; ni++) {
            int row = wc + ni * 16 + ln;
            bf[ni] = *(half8*)(sB + row * 256 + (koff ^ ((row & 7) << 4)));
        }
        #pragma unroll
        for (int mi = 0; mi < 4; mi++)
            #pragma unroll
            for (int ni = 0; ni < 4; ni++)
                acc[mi][ni] = __builtin_amdgcn_mfma_f32_16x16x32_f16(af[mi], bf[ni], acc[mi][ni], 0, 0, 0);
    }

    float dv[4][4];
    #pragma unroll
    for (int mi = 0; mi < 4; mi++)
        #pragma unroll
        for (int r = 0; r < 4; r++) {
            int grow = r0 + wr + mi * 16 + q * 4 + r;
            dv[mi][r] = dinv[grow < NN ? grow : 0];
        }
    #pragma unroll
    for (int mi = 0; mi < 4; mi++) {
        #pragma unroll
        for (int r = 0; r < 4; r++) {
            int grow = r0 + wr + mi * 16 + q * 4 + r;
            if (grow < NN) {
                #pragma unroll
                for (int ni = 0; ni < 4; ni++) {
                    int gcol = wc + ni * 16 + ln;
                    float v = acc[mi][ni][r] * dv[mi][r];
                    unsigned qb = (unsigned)__builtin_amdgcn_cvt_pk_fp8_f32(v, v, 0, false) & 0xffu;
                    T[(size_t)grow * HH + gcol] = (unsigned char)qb;
                }
            }
        }
    }
}

// ---------------- aggregation: O[n](fp16) = relu?( dinv[n]*sum_{csr} T8[src] + bias ) ----------------
// wave = 1 node; lane = (eslot 0..7) x (li 0..7: 16B of the 128B fp8 row).
// SOFTWARE PIPELINE: gather i+1 issued before converting gather i (2 loads in flight).
__global__ __launch_bounds__(256) void k_agg(const unsigned char* __restrict__ T, __half* __restrict__ O,
                                             const int* __restrict__ row_off, const int* __restrict__ csr_src,
                                             const float* __restrict__ dinv,
                                             const float* __restrict__ bias, int relu) {
    int gt = blockIdx.x * blockDim.x + threadIdx.x;
    int n = gt >> 6;
    if (n >= NN) return;
    int lane = threadIdx.x & 63;
    int eslot = lane >> 3;                     // 0..7 edge slot
    int li = lane & 7;                         // 16B chunk of the 128B row

    int beg = row_off[n], end = row_off[n + 1];
    int nit = (end - beg + 7) >> 3;            // >= 1 (self edge)

    floatx2 acc2[8];
    #pragma unroll
    for (int c = 0; c < 8; c++) acc2[c] = (floatx2)0.f;

    // prologue: issue gather 0
    int p = beg + eslot;
    int s0raw = csr_src[p];                    // csr_src padded: always-valid address
    int s0 = (p < end) ? s0raw : NN;           // fp8 zero row for invalid slots
    uint4 r0 = *(const uint4*)(T + ((size_t)s0 << 7) + li * 16);

    for (int i = 1; i < nit; i++) {
        p += 8;
        // issue gather i before converting gather i-1
        int s1raw = csr_src[p];
        int s1 = (p < end) ? s1raw : NN;
        uint4 r1 = *(const uint4*)(T + ((size_t)s1 << 7) + li * 16);
        unsigned dw[4] = {r0.x, r0.y, r0.z, r0.w};
        #pragma unroll
        for (int j = 0; j < 4; j++) {
            acc2[2 * j]     += __builtin_amdgcn_cvt_pk_f32_fp8(dw[j], false);
            acc2[2 * j + 1] += __builtin_amdgcn_cvt_pk_f32_fp8(dw[j], true);
        }
        r0 = r1;
    }
    // epilogue: convert last gather
    {
        unsigned dw[4] = {r0.x, r0.y, r0.z, r0.w};
        #pragma unroll
        for (int j = 0; j < 4; j++) {
            acc2[2 * j]     += __builtin_amdgcn_cvt_pk_f32_fp8(dw[j], false);
            acc2[2 * j + 1] += __builtin_amdgcn_cvt_pk_f32_fp8(dw[j], true);
        }
    }

    // pack to fp16 pairs, reduce across 8 edge slots (xor 8,16,32)
    union { __half2 h; int i; } r[8];
    #pragma unroll
    for (int j = 0; j < 8; j++) r[j].h = __floats2half2_rn(acc2[j].x, acc2[j].y);
    #pragma unroll
    for (int m = 8; m <= 32; m <<= 1) {
        #pragma unroll
        for (int j = 0; j < 8; j++) {
            union { __half2 h; int i; } v;
            v.i = __shfl_xor(r[j].i, m, 64);
            r[j].h = __hadd2(r[j].h, v.h);
        }
    }

    if (eslot == 0) {                          // lanes 0..7 hold li = 0..7 (16 cols each)
        float dn = dinv[n];
        float o[16];
        #pragma unroll
        for (int j = 0; j < 8; j++) {
            float2 f = __half22float2(r[j].h);
            o[2 * j] = f.x; o[2 * j + 1] = f.y;
        }
        const float* bp = bias + li * 16;
        #pragma unroll
        for (int k = 0; k < 16; k++) {
            o[k] = dn * o[k] + bp[k];
            if (relu) o[k] = fmaxf(o[k], 0.f);
        }
        union { uint4 u[2]; __half2 h2[8]; } pk;
        #pragma unroll
        for (int j = 0; j < 8; j++) pk.h2[j] = __floats2half2_rn(o[2 * j], o[2 * j + 1]);
        uint4* Op = (uint4*)((char*)O + (size_t)n * 256 + li * 32);
        Op[0] = pk.u[0];
        Op[1] = pk.u[1];
    }
}

// ---------------- pooling: batch sorted -> run-length accumulate (node-major fp16 in) ----------------
__global__ __launch_bounds__(128) void k_pool(const __half* __restrict__ Hm, const int* __restrict__ batch,
                                              float* __restrict__ pooled, float* __restrict__ gcnt) {
    int j = threadIdx.x;
    int n0 = blockIdx.x * 64;
    int nend = n0 + 64; if (nend > NN) nend = NN;
    float acc = 0.f;
    int gcur = batch[n0];
    int run = 0;
    for (int n = n0; n < nend; n++) {
        int g = batch[n];
        if (g != gcur) {
            atomicAdd(&pooled[gcur * HH + j], acc);
            if (j == 0) atomicAdd(&gcnt[gcur], (float)run);
            acc = 0.f; run = 0; gcur = g;
        }
        acc += __half2float(Hm[(size_t)n * HH + j]);
        run++;
    }
    atomicAdd(&pooled[gcur * HH + j], acc);
    if (j == 0) atomicAdd(&gcnt[gcur], (float)run);
}

// ---------------- classifier ----------------
__global__ void k_classify(const float* __restrict__ pooled, const float* __restrict__ gcnt,
                           const float* __restrict__ Wc, const float* __restrict__ bc,
                           float* __restrict__ out) {
    int idx = blockIdx.x * blockDim.x + threadIdx.x;
    if (idx >= GG * CC) return;
    int g = idx >> 5, c = idx & 31;
    float inv = 1.f / fmaxf(gcnt[g], 1.f);
    float acc = bc[c];
    for (int k = 0; k < HH; k++) acc += pooled[g * HH + k] * inv * Wc[k * CC + c];
    out[idx] = acc;
}

extern "C" void kernel_launch(void* const* d_in, const int* in_sizes, int n_in,
                              void* d_out, int out_size, void* d_ws, size_t ws_size,
                              hipStream_t stream) {
    const float* x     = (const float*)d_in[0];
    const int*   ei    = (const int*)d_in[1];
    const int*   batch = (const int*)d_in[2];
    const float* W1 = (const float*)d_in[3];  const float* b1 = (const float*)d_in[4];
    const float* W2 = (const float*)d_in[5];  const float* b2 = (const float*)d_in[6];
    const float* W3 = (const float*)d_in[7];  const float* b3 = (const float*)d_in[8];
    const float* Wc = (const float*)d_in[9];  const float* bc = (const float*)d_in[10];
    float* out = (float*)d_out;

    const int* src = ei;
    const int* dst = ei + EE;

    char* w = (char*)d_ws;
    __half*        h16     = (__half*)w;        w += (size_t)NN * HH * sizeof(__half);     // 25.6 MB node-major
    unsigned char* t8      = (unsigned char*)w; w += (size_t)(NN + 1) * HH;                // 12.8 MB fp8 + zero row
    __half*        wt16    = (__half*)w;        w += (size_t)3 * HH * HH * sizeof(__half);
    float*         dinv    = (float*)w;         w += (size_t)NN * sizeof(float);
    int*           csr_src = (int*)w;           w += (size_t)(ETOT + 32) * sizeof(int);    // +pad for 8-slot overread
    int*           staged  = (int*)w;           w += (size_t)EE * sizeof(int);
    int*           mat     = (int*)w;           w += (size_t)MATL * sizeof(int);
    int*           matscan = (int*)w;           w += (size_t)(MATL + 1) * sizeof(int);
    int*           row_off = (int*)w;           w += (size_t)(NN + 1) * sizeof(int);
    int*           counts  = (int*)w;           w += (size_t)NN * sizeof(int);
    int*           bsum    = (int*)w;           w += (size_t)1024 * sizeof(int);
    int*           boff    = (int*)w;           w += (size_t)1024 * sizeof(int);
    float*         pooled  = (float*)w;         w += (size_t)GG * HH * sizeof(float);
    float*         gcnt    = (float*)w;         w += (size_t)GG * sizeof(float);

    const int matblk = (MATL + 1023) / 1024;   // 49
    const int cntblk = (NN + 1023) / 1024;     // 98

    // prep (W transpose + accumulator init, one kernel)
    k_prep <<<3 + (GG * HH + 255) / 256, 256, 0, stream>>>(W1, W2, W3, wt16, pooled, gcnt, t8);

    // CSR build: bucketed two-phase partition (multi-block scans)
    k_hist      <<<NBLK, 256, 0, stream>>>(dst, mat);
    k_psumG     <<<matblk, 1024, 0, stream>>>(mat, bsum, MATL);
    k_bscanG    <<<1, 1024, 0, stream>>>(bsum, boff, matblk);
    k_localG    <<<matblk, 1024, 0, stream>>>(mat, boff, matscan, MATL, EE);
    k_binscatter<<<NBLK, 256, 0, stream>>>(src, dst, matscan, staged);
    k_bcount    <<<NB, 256, 0, stream>>>(matscan, staged, counts, dinv);
    k_psumG     <<<cntblk, 1024, 0, stream>>>(counts, bsum, NN);
    k_bscanG    <<<1, 1024, 0, stream>>>(bsum, boff, cntblk);
    k_localG    <<<cntblk, 1024, 0, stream>>>(counts, boff, row_off, NN, ETOT);
    k_place     <<<NB, 256, 0, stream>>>(matscan, staged, row_off, csr_src);

    const int gemm_grid = (NN + 127) / 128;   // 782
    const int agg_grid  = NN * 64 / 256;      // 25000 (one wave per node)

    // layer 1 (fp32 input staged+converted in-kernel)
    k_gemm<1><<<gemm_grid, 256, 0, stream>>>(x, wt16,                dinv, t8);
    k_agg    <<<agg_grid, 256, 0, stream>>>(t8, h16, row_off, csr_src, dinv, b1, 1);
    // layer 2
    k_gemm<0><<<gemm_grid, 256, 0, stream>>>(h16, wt16 + HH * HH,    dinv, t8);
    k_agg    <<<agg_grid, 256, 0, stream>>>(t8, h16, row_off, csr_src, dinv, b2, 1);
    // layer 3 (no relu)
    k_gemm<0><<<gemm_grid, 256, 0, stream>>>(h16, wt16 + 2 * HH * HH, dinv, t8);
    k_agg    <<<agg_grid, 256, 0, stream>>>(t8, h16, row_off, csr_src, dinv, b3, 0);

    // pool + classify
    k_pool<<<(NN + 63) / 64, 128, 0, stream>>>(h16, batch, pooled, gcnt);
    k_classify<<<(GG * CC + 255) / 256, 256, 0, stream>>>(pooled, gcnt, Wc, bc, out);
}